// Round 2
// baseline (23101.820 us; speedup 1.0000x reference)
//
#include <hip/hip_runtime.h>

#define T_STEPS 512
#define BATCH   128
#define SDIM    1024
#define ODIM    256
#define NWG     160
#define NTHR    256

typedef __attribute__((ext_vector_type(8))) short bf16x8;
typedef __attribute__((ext_vector_type(4))) float f32x4;

// ws layout (bytes)
#define WR_OFF   0                        // ushort[1024*1024]  2 MB  (w_r bf16)
#define WO_OFF   (2u*1024*1024)           // ushort[256*1024] 512 KB  (w_o bf16)
#define H_OFF    (WO_OFF + 512u*1024)     // float [128*1024] 512 KB  (h state)
#define TH0_OFF  (H_OFF + 512u*1024)      // ushort[128*1024] 256 KB  (tanh(h) ping)
#define TH1_OFF  (TH0_OFF + 256u*1024)    // ushort[128*1024] 256 KB  (tanh(h) pong)
#define BAR_OFF  (TH1_OFF + 256u*1024)    // unsigned[2]: {count, generation}

__device__ __forceinline__ unsigned short f2bf(float f) {
    union { float f; unsigned u; } v; v.f = f;
    unsigned r = v.u + 0x7fffu + ((v.u >> 16) & 1u);   // round-to-nearest-even
    return (unsigned short)(r >> 16);
}

__device__ __forceinline__ void gbar(unsigned* cnt, unsigned* gen, unsigned target) {
    __threadfence();          // release this WG's global writes (agent scope)
    __syncthreads();
    if (threadIdx.x == 0) {
        unsigned old = __hip_atomic_fetch_add(cnt, 1u, __ATOMIC_ACQ_REL,
                                              __HIP_MEMORY_SCOPE_AGENT);
        if (old == (unsigned)(NWG - 1)) {
            __hip_atomic_store(cnt, 0u, __ATOMIC_RELAXED, __HIP_MEMORY_SCOPE_AGENT);
            __hip_atomic_store(gen, target, __ATOMIC_RELEASE, __HIP_MEMORY_SCOPE_AGENT);
        } else {
            unsigned g;
            do {
                __builtin_amdgcn_s_sleep(1);
                g = __hip_atomic_load(gen, __ATOMIC_ACQUIRE, __HIP_MEMORY_SCOPE_AGENT);
            } while (g < target);
        }
    }
    __syncthreads();
    __threadfence();          // make remote writes visible to all threads' loads
}

__global__ __launch_bounds__(NTHR, 1) void trnn_persistent(
    const float* __restrict__ x, const float* __restrict__ h_init,
    const float* __restrict__ w_r, const float* __restrict__ b_r,
    const float* __restrict__ w_o, const float* __restrict__ b_o,
    float* __restrict__ out, char* __restrict__ ws)
{
    unsigned short* wr_bf = (unsigned short*)(ws + WR_OFF);
    unsigned short* wo_bf = (unsigned short*)(ws + WO_OFF);
    float*          hbuf  = (float*)(ws + H_OFF);
    unsigned short* th0   = (unsigned short*)(ws + TH0_OFF);
    unsigned short* th1   = (unsigned short*)(ws + TH1_OFF);
    unsigned*       bar   = (unsigned*)(ws + BAR_OFF);

    const int wg  = blockIdx.x;
    const int tid = threadIdx.x;
    const int gtid = wg * NTHR + tid;
    const int gstr = NWG * NTHR;

    // ---- init: convert weights to bf16, seed h and th0 = tanh(h_init) ----
    for (int i = gtid; i < SDIM * SDIM; i += gstr) wr_bf[i] = f2bf(w_r[i]);
    for (int i = gtid; i < ODIM * SDIM; i += gstr) wo_bf[i] = f2bf(w_o[i]);
    for (int i = gtid; i < BATCH * SDIM; i += gstr) {
        float v = h_init[i];
        hbuf[i] = v;
        th0[i] = f2bf(tanhf(v));
    }

    unsigned target = 1;
    gbar(bar, bar + 1, target); // barrier after init
    target++;

    const int lane = tid & 63;
    const int wv   = tid >> 6;         // wave 0..3
    const int row  = lane & 15;
    const int quad = lane >> 4;        // 0..3

    // role decode
    const bool is_g1 = (wg < 128);
    // GEMM1: tile [16 b x 64 j]; 8 b-tiles x 16 j-tiles
    const int g1_bbase = (wg >> 4) * 16;
    const int g1_jbase = (wg & 15) * 64 + wv * 16;
    // GEMM2: tile [16 b x 64 o]; 8 b-tiles x 4 o-tiles (wg-128 in 0..31)
    const int wg2 = wg - 128;
    const int g2_bbase = (wg2 >> 2) * 16;
    const int g2_obase = (wg2 & 3) * 64 + wv * 16;

    for (int t = 0; t <= T_STEPS; ++t) {
        const unsigned short* cur = (t & 1) ? th1 : th0;   // th_t
        unsigned short*       nxt = (t & 1) ? th0 : th1;   // th_{t+1}

        if (is_g1) {
            if (t < T_STEPS) {
                // h_{t+1} = 0.75 h_t + 0.25 (th_t @ w_r^T + b_r); th_{t+1} = tanh(h_{t+1})
                f32x4 acc = {0.f, 0.f, 0.f, 0.f};
                const unsigned short* aptr = cur   + (g1_bbase + row) * SDIM + quad * 8;
                const unsigned short* bptr = wr_bf + (g1_jbase + row) * SDIM + quad * 8;
                #pragma unroll 8
                for (int kk = 0; kk < 32; ++kk) {
                    bf16x8 af = *(const bf16x8*)(aptr + kk * 32);
                    bf16x8 bf = *(const bf16x8*)(bptr + kk * 32);
                    acc = __builtin_amdgcn_mfma_f32_16x16x32_bf16(af, bf, acc, 0, 0, 0);
                }
                const int j = g1_jbase + row;
                const float brj = b_r[j];
                const int b0 = g1_bbase + quad * 4;
                #pragma unroll
                for (int r = 0; r < 4; ++r) {
                    const int idx = (b0 + r) * SDIM + j;
                    float hn = 0.75f * hbuf[idx] + 0.25f * (acc[r] + brj);
                    hbuf[idx] = hn;
                    nxt[idx] = f2bf(tanhf(hn));
                }
            }
        } else {
            if (t >= 1) {
                // out[t-1] = th_t @ w_o^T + b_o - x[t-1]
                f32x4 acc = {0.f, 0.f, 0.f, 0.f};
                const unsigned short* aptr = cur   + (g2_bbase + row) * SDIM + quad * 8;
                const unsigned short* bptr = wo_bf + (g2_obase + row) * SDIM + quad * 8;
                #pragma unroll 8
                for (int kk = 0; kk < 32; ++kk) {
                    bf16x8 af = *(const bf16x8*)(aptr + kk * 32);
                    bf16x8 bf = *(const bf16x8*)(bptr + kk * 32);
                    acc = __builtin_amdgcn_mfma_f32_16x16x32_bf16(af, bf, acc, 0, 0, 0);
                }
                const int o = g2_obase + row;
                const float boo = b_o[o];
                const int b0 = g2_bbase + quad * 4;
                const int tbase = (t - 1) * BATCH * ODIM;
                #pragma unroll
                for (int r = 0; r < 4; ++r) {
                    const int idx = tbase + (b0 + r) * ODIM + o;
                    out[idx] = acc[r] + boo - x[idx];
                }
            }
        }

        if (t < T_STEPS) {
            gbar(bar, bar + 1, target);
            target++;
        }
    }
}

extern "C" void kernel_launch(void* const* d_in, const int* in_sizes, int n_in,
                              void* d_out, int out_size, void* d_ws, size_t ws_size,
                              hipStream_t stream) {
    const float* x      = (const float*)d_in[0];
    const float* h_init = (const float*)d_in[1];
    const float* w_r    = (const float*)d_in[2];
    const float* b_r    = (const float*)d_in[3];
    const float* w_o    = (const float*)d_in[4];
    const float* b_o    = (const float*)d_in[5];
    float* out = (float*)d_out;
    char*  ws  = (char*)d_ws;

    // zero the barrier state (ws is poisoned 0xAA before every launch)
    (void)hipMemsetAsync(ws + BAR_OFF, 0, 128, stream);

    trnn_persistent<<<dim3(NWG), dim3(NTHR), 0, stream>>>(
        x, h_init, w_r, b_r, w_o, b_o, out, ws);
}

// Round 3
// 17251.295 us; speedup vs baseline: 1.3391x; 1.3391x over previous
//
#include <hip/hip_runtime.h>

#define T_STEPS 512
#define BATCH   128
#define SDIM    1024
#define ODIM    256
#define NWG     160
#define NTHR    256

typedef __attribute__((ext_vector_type(8))) short bf16x8;
typedef __attribute__((ext_vector_type(4))) float f32x4;

// ws layout (bytes)
#define WR_OFF   0                        // ushort[1024*1024]  2 MB  (w_r bf16)
#define WO_OFF   (2u*1024*1024)           // ushort[256*1024] 512 KB  (w_o bf16)
#define H_OFF    (WO_OFF + 512u*1024)     // float [128*1024] 512 KB  (h state)
#define TH0_OFF  (H_OFF + 512u*1024)      // ushort[128*1024] 256 KB  (tanh(h) ping)
#define TH1_OFF  (TH0_OFF + 256u*1024)    // ushort[128*1024] 256 KB  (tanh(h) pong)
#define FLAG_OFF (TH1_OFF + 256u*1024)    // unsigned flags[NWG], 64B apart (10 KB)
#define GEN_OFF  (FLAG_OFF + NWG*64u)     // unsigned generation
#define FLAG_STRIDE 16                    // words -> 64 B per flag line

__device__ __forceinline__ unsigned short f2bf(float f) {
    union { float f; unsigned u; } v; v.f = f;
    unsigned r = v.u + 0x7fffu + ((v.u >> 16) & 1u);   // round-to-nearest-even
    return (unsigned short)(r >> 16);
}

// Contention-free grid barrier:
//  - every WG: release fence, then plain relaxed agent store to its own flag line
//  - master WG 0: threads 0..NWG-1 poll the NWG flags in parallel, then one
//    release store to `gen`
//  - other WGs: thread 0 polls `gen` (relaxed agent load = L2-bypass, no
//    full-cache invalidate per poll), acquire fence after.
__device__ __forceinline__ void gbar(unsigned* flags, unsigned* gen,
                                     unsigned target, int wg, int tid) {
    __threadfence();              // release this WG's global writes
    __syncthreads();
    if (wg == 0) {
        if (tid == 0)
            __hip_atomic_store(&flags[0], target, __ATOMIC_RELAXED,
                               __HIP_MEMORY_SCOPE_AGENT);
        if (tid < NWG) {
            while (__hip_atomic_load(&flags[tid * FLAG_STRIDE], __ATOMIC_RELAXED,
                                     __HIP_MEMORY_SCOPE_AGENT) < target)
                __builtin_amdgcn_s_sleep(1);
        }
        __syncthreads();
        __threadfence();
        if (tid == 0)
            __hip_atomic_store(gen, target, __ATOMIC_RELAXED,
                               __HIP_MEMORY_SCOPE_AGENT);
    } else {
        if (tid == 0) {
            __hip_atomic_store(&flags[wg * FLAG_STRIDE], target, __ATOMIC_RELAXED,
                               __HIP_MEMORY_SCOPE_AGENT);
            while (__hip_atomic_load(gen, __ATOMIC_RELAXED,
                                     __HIP_MEMORY_SCOPE_AGENT) < target)
                __builtin_amdgcn_s_sleep(1);
        }
        __syncthreads();
    }
    __threadfence();              // acquire: make remote writes visible
}

__global__ __launch_bounds__(NTHR, 1) void trnn_persistent(
    const float* __restrict__ x, const float* __restrict__ h_init,
    const float* __restrict__ w_r, const float* __restrict__ b_r,
    const float* __restrict__ w_o, const float* __restrict__ b_o,
    float* __restrict__ out, char* __restrict__ ws)
{
    unsigned short* wr_bf = (unsigned short*)(ws + WR_OFF);
    unsigned short* wo_bf = (unsigned short*)(ws + WO_OFF);
    float*          hbuf  = (float*)(ws + H_OFF);
    unsigned short* th0   = (unsigned short*)(ws + TH0_OFF);
    unsigned short* th1   = (unsigned short*)(ws + TH1_OFF);
    unsigned*       flags = (unsigned*)(ws + FLAG_OFF);
    unsigned*       gen   = (unsigned*)(ws + GEN_OFF);

    const int wg  = blockIdx.x;
    const int tid = threadIdx.x;
    const int gtid = wg * NTHR + tid;
    const int gstr = NWG * NTHR;

    // ---- init: convert weights to bf16, seed h and th0 = tanh(h_init) ----
    for (int i = gtid; i < SDIM * SDIM; i += gstr) wr_bf[i] = f2bf(w_r[i]);
    for (int i = gtid; i < ODIM * SDIM; i += gstr) wo_bf[i] = f2bf(w_o[i]);
    for (int i = gtid; i < BATCH * SDIM; i += gstr) {
        float v = h_init[i];
        hbuf[i] = v;
        th0[i] = f2bf(tanhf(v));
    }

    unsigned target = 1;
    gbar(flags, gen, target, wg, tid);   // barrier after init
    target++;

    const int lane = tid & 63;
    const int wv   = tid >> 6;         // wave 0..3
    const int row  = lane & 15;
    const int quad = lane >> 4;        // 0..3

    // role decode
    const bool is_g1 = (wg < 128);
    // GEMM1: tile [16 b x 64 j]; 8 b-tiles x 16 j-tiles
    const int g1_bbase = (wg >> 4) * 16;
    const int g1_jbase = (wg & 15) * 64 + wv * 16;
    // GEMM2: tile [16 b x 64 o]; 8 b-tiles x 4 o-tiles (wg-128 in 0..31)
    const int wg2 = wg - 128;
    const int g2_bbase = (wg2 >> 2) * 16;
    const int g2_obase = (wg2 & 3) * 64 + wv * 16;

    const int bbase = is_g1 ? g1_bbase : g2_bbase;

    // ---- weight-stationary: preload this wave's 32 B-fragments (128 VGPRs) ----
    const unsigned short* bsrc =
        (is_g1 ? wr_bf + (g1_jbase + row) * SDIM
               : wo_bf + (g2_obase + row) * SDIM) + quad * 8;
    bf16x8 bw[32];
    #pragma unroll
    for (int kk = 0; kk < 32; ++kk) bw[kk] = *(const bf16x8*)(bsrc + kk * 32);

    for (int t = 0; t <= T_STEPS; ++t) {
        const unsigned short* cur = (t & 1) ? th1 : th0;   // th_t
        unsigned short*       nxt = (t & 1) ? th0 : th1;   // th_{t+1}

        const bool active = is_g1 ? (t < T_STEPS) : (t >= 1);
        if (active) {
            f32x4 acc = {0.f, 0.f, 0.f, 0.f};
            const unsigned short* aptr = cur + (bbase + row) * SDIM + quad * 8;
            #pragma unroll
            for (int kk = 0; kk < 32; ++kk) {
                bf16x8 af = *(const bf16x8*)(aptr + kk * 32);
                acc = __builtin_amdgcn_mfma_f32_16x16x32_bf16(af, bw[kk], acc, 0, 0, 0);
            }
            if (is_g1) {
                // h' = 0.75 h + 0.25 (th @ w_r^T + b_r); th' = tanh(h')
                const int j = g1_jbase + row;
                const float brj = b_r[j];
                const int b0 = g1_bbase + quad * 4;
                #pragma unroll
                for (int r = 0; r < 4; ++r) {
                    const int idx = (b0 + r) * SDIM + j;
                    float hn = 0.75f * hbuf[idx] + 0.25f * (acc[r] + brj);
                    hbuf[idx] = hn;
                    nxt[idx] = f2bf(tanhf(hn));
                }
            } else {
                // out[t-1] = th_t @ w_o^T + b_o - x[t-1]
                const int o = g2_obase + row;
                const float boo = b_o[o];
                const int b0 = g2_bbase + quad * 4;
                const int tbase = (t - 1) * BATCH * ODIM;
                #pragma unroll
                for (int r = 0; r < 4; ++r) {
                    const int idx = tbase + (b0 + r) * ODIM + o;
                    out[idx] = acc[r] + boo - x[idx];
                }
            }
        }

        if (t < T_STEPS) {
            gbar(flags, gen, target, wg, tid);
            target++;
        }
    }
}

extern "C" void kernel_launch(void* const* d_in, const int* in_sizes, int n_in,
                              void* d_out, int out_size, void* d_ws, size_t ws_size,
                              hipStream_t stream) {
    const float* x      = (const float*)d_in[0];
    const float* h_init = (const float*)d_in[1];
    const float* w_r    = (const float*)d_in[2];
    const float* b_r    = (const float*)d_in[3];
    const float* w_o    = (const float*)d_in[4];
    const float* b_o    = (const float*)d_in[5];
    float* out = (float*)d_out;
    char*  ws  = (char*)d_ws;

    // zero the barrier flags + generation (ws is poisoned 0xAA before launch)
    (void)hipMemsetAsync(ws + FLAG_OFF, 0, NWG * 64 + 64, stream);

    trnn_persistent<<<dim3(NWG), dim3(NTHR), 0, stream>>>(
        x, h_init, w_r, b_r, w_o, b_o, out, ws);
}

// Round 4
// 2450.410 us; speedup vs baseline: 9.4277x; 7.0402x over previous
//
#include <hip/hip_runtime.h>

#define T_STEPS 512
#define BATCH   128
#define SDIM    1024
#define ODIM    256
#define NWG     160
#define NTHR    256

typedef __attribute__((ext_vector_type(8))) short bf16x8;
typedef __attribute__((ext_vector_type(4))) float f32x4;
typedef __attribute__((ext_vector_type(4))) unsigned int u32x4;

// ws layout (bytes)
#define WR_OFF   0                        // ushort[1024*1024]  2 MB  (w_r bf16)
#define WO_OFF   (2u*1024*1024)           // ushort[256*1024] 512 KB  (w_o bf16)
#define H_OFF    (WO_OFF + 512u*1024)     // float [128*1024] 512 KB  (h state)
#define TH0_OFF  (H_OFF + 512u*1024)      // ushort[128*1024] 256 KB  (tanh(h) ping)
#define TH1_OFF  (TH0_OFF + 256u*1024)    // ushort[128*1024] 256 KB  (tanh(h) pong)
#define FLAG_OFF (TH1_OFF + 256u*1024)    // unsigned flags[NWG], 64 B apart
#define FLAG_STRIDE 16                    // words -> 64 B per flag line

#define LDS_ROW  1032                     // 1024 shorts + 8 pad (16 B) per row

__device__ __forceinline__ unsigned short f2bf(float f) {
    union { float f; unsigned u; } v; v.f = f;
    unsigned r = v.u + 0x7fffu + ((v.u >> 16) & 1u);   // round-to-nearest-even
    return (unsigned short)(r >> 16);
}

// sc1 (device-coherent) 16 B load: bypasses per-XCD L2, serviced at L3.
#define LOAD16_SC1(d, p) \
    asm volatile("global_load_dwordx4 %0, %1, off sc0 sc1" : "=v"(d) : "v"(p))
// Drain loads; ties the 8 staged values so the compiler can't use them earlier.
#define WAIT_HOLD8(a,b,c,d,e,f,g,h)                                    \
    asm volatile("s_waitcnt vmcnt(0)"                                  \
                 : "+v"(a), "+v"(b), "+v"(c), "+v"(d),                 \
                   "+v"(e), "+v"(f), "+v"(g), "+v"(h) :: "memory")

__device__ __forceinline__ void st_sc1_u16(unsigned short* p, unsigned short v) {
    __hip_atomic_store(p, v, __ATOMIC_RELAXED, __HIP_MEMORY_SCOPE_AGENT);
}
__device__ __forceinline__ void st_sc1_f32(float* p, float v) {
    __hip_atomic_store(p, v, __ATOMIC_RELAXED, __HIP_MEMORY_SCOPE_AGENT);
}

// Single-round-trip group barrier: post own flag, poll all 20 member flags.
// No fences: producers drained their sc1 stores (vmcnt0) before posting, so
// once a flag reads `target` the data is at the L3 coherence point.
__device__ __forceinline__ void group_bar(unsigned* flags, int g, int wg,
                                          int tid, unsigned target) {
    asm volatile("s_waitcnt vmcnt(0)" ::: "memory");
    __syncthreads();
    if (tid == 0)
        __hip_atomic_store(&flags[wg * FLAG_STRIDE], target,
                           __ATOMIC_RELAXED, __HIP_MEMORY_SCOPE_AGENT);
    if (tid < 20) {
        const int m = (tid < 16) ? (g * 16 + tid) : (128 + g * 4 + (tid - 16));
        while (__hip_atomic_load(&flags[m * FLAG_STRIDE], __ATOMIC_RELAXED,
                                 __HIP_MEMORY_SCOPE_AGENT) < target) {}
    }
    __syncthreads();
    asm volatile("" ::: "memory");
}

__global__ __launch_bounds__(NTHR, 1) void trnn_persistent(
    const float* __restrict__ x, const float* __restrict__ h_init,
    const float* __restrict__ w_r, const float* __restrict__ b_r,
    const float* __restrict__ w_o, const float* __restrict__ b_o,
    float* __restrict__ out, char* __restrict__ ws)
{
    unsigned short* wr_bf = (unsigned short*)(ws + WR_OFF);
    unsigned short* wo_bf = (unsigned short*)(ws + WO_OFF);
    float*          hbuf  = (float*)(ws + H_OFF);
    unsigned short* th0   = (unsigned short*)(ws + TH0_OFF);
    unsigned short* th1   = (unsigned short*)(ws + TH1_OFF);
    unsigned*       flags = (unsigned*)(ws + FLAG_OFF);

    __shared__ unsigned short lds_th[16 * LDS_ROW];   // 33 KB

    const int wg  = blockIdx.x;
    const int tid = threadIdx.x;
    const int gtid = wg * NTHR + tid;
    const int gstr = NWG * NTHR;

    // ---- init: bf16 weights, h state, th0 = tanh(h_init). All shared data
    // written sc1 (write-through to L3) so no fences are ever needed. ----
    for (int i = gtid; i < SDIM * SDIM; i += gstr) st_sc1_u16(&wr_bf[i], f2bf(w_r[i]));
    for (int i = gtid; i < ODIM * SDIM; i += gstr) st_sc1_u16(&wo_bf[i], f2bf(w_o[i]));
    for (int i = gtid; i < BATCH * SDIM; i += gstr) {
        float v = h_init[i];
        st_sc1_f32(&hbuf[i], v);
        st_sc1_u16(&th0[i], f2bf(tanhf(v)));
    }

    // ---- global barrier after init (all-to-all over 160 flags, once) ----
    {
        asm volatile("s_waitcnt vmcnt(0)" ::: "memory");
        __syncthreads();
        if (tid == 0)
            __hip_atomic_store(&flags[wg * FLAG_STRIDE], 1u,
                               __ATOMIC_RELAXED, __HIP_MEMORY_SCOPE_AGENT);
        if (tid < NWG) {
            while (__hip_atomic_load(&flags[tid * FLAG_STRIDE], __ATOMIC_RELAXED,
                                     __HIP_MEMORY_SCOPE_AGENT) < 1u) {}
        }
        __syncthreads();
        asm volatile("" ::: "memory");
    }
    unsigned target = 2;

    const int lane = tid & 63;
    const int wv   = tid >> 6;         // wave 0..3
    const int row  = lane & 15;
    const int quad = lane >> 4;        // 0..3

    // role decode
    const bool is_g1 = (wg < 128);
    const int g1_bbase = (wg >> 4) * 16;
    const int g1_jbase = (wg & 15) * 64 + wv * 16;
    const int wg2 = wg - 128;
    const int g2_bbase = (wg2 >> 2) * 16;
    const int g2_obase = (wg2 & 3) * 64 + wv * 16;

    const int bbase = is_g1 ? g1_bbase : g2_bbase;
    const int grp   = is_g1 ? (wg >> 4) : (wg2 >> 2);

    // ---- weight-stationary: preload this wave's 32 B-fragments (128 VGPRs).
    // Normal loads are safe: lines were sc1-written, no L2 copy is stale. ----
    const unsigned short* bsrc =
        (is_g1 ? wr_bf + (g1_jbase + row) * SDIM
               : wo_bf + (g2_obase + row) * SDIM) + quad * 8;
    bf16x8 bw[32];
    #pragma unroll
    for (int kk = 0; kk < 32; ++kk) bw[kk] = *(const bf16x8*)(bsrc + kk * 32);

    // staging map: thread -> (row r_st, 8 chunks of 16 B strided 128 shorts)
    const int r_st = tid >> 4;
    const int c0   = tid & 15;

    for (int t = 0; t <= T_STEPS; ++t) {
        const unsigned short* cur = (t & 1) ? th1 : th0;   // th_t
        unsigned short*       nxt = (t & 1) ? th0 : th1;   // th_{t+1}

        const bool active = is_g1 ? (t < T_STEPS) : (t >= 1);
        if (active) {
            // ---- stage th tile [16 x 1024] into LDS via sc1 loads ----
            const unsigned short* src = cur + (bbase + r_st) * SDIM + c0 * 8;
            u32x4 d0, d1, d2, d3, d4, d5, d6, d7;
            LOAD16_SC1(d0, src + 0 * 128);
            LOAD16_SC1(d1, src + 1 * 128);
            LOAD16_SC1(d2, src + 2 * 128);
            LOAD16_SC1(d3, src + 3 * 128);
            LOAD16_SC1(d4, src + 4 * 128);
            LOAD16_SC1(d5, src + 5 * 128);
            LOAD16_SC1(d6, src + 6 * 128);
            LOAD16_SC1(d7, src + 7 * 128);
            WAIT_HOLD8(d0, d1, d2, d3, d4, d5, d6, d7);
            unsigned short* dst = &lds_th[r_st * LDS_ROW + c0 * 8];
            *(u32x4*)(dst + 0 * 128) = d0;
            *(u32x4*)(dst + 1 * 128) = d1;
            *(u32x4*)(dst + 2 * 128) = d2;
            *(u32x4*)(dst + 3 * 128) = d3;
            *(u32x4*)(dst + 4 * 128) = d4;
            *(u32x4*)(dst + 5 * 128) = d5;
            *(u32x4*)(dst + 6 * 128) = d6;
            *(u32x4*)(dst + 7 * 128) = d7;
            __syncthreads();

            // ---- MFMA over K=1024 ----
            f32x4 acc = {0.f, 0.f, 0.f, 0.f};
            const unsigned short* arow = &lds_th[row * LDS_ROW + quad * 8];
            #pragma unroll
            for (int kk = 0; kk < 32; ++kk) {
                bf16x8 af = *(const bf16x8*)(arow + kk * 32);
                acc = __builtin_amdgcn_mfma_f32_16x16x32_bf16(af, bw[kk], acc, 0, 0, 0);
            }

            if (is_g1) {
                // h' = 0.75 h + 0.25 (th w_r^T + b_r); th' = tanh(h') (sc1)
                const int j = g1_jbase + row;
                const float brj = b_r[j];
                const int b0 = g1_bbase + quad * 4;
                #pragma unroll
                for (int r = 0; r < 4; ++r) {
                    const int idx = (b0 + r) * SDIM + j;
                    float hn = 0.75f * hbuf[idx] + 0.25f * (acc[r] + brj);
                    hbuf[idx] = hn;                 // private to this WG: normal
                    st_sc1_u16(&nxt[idx], f2bf(tanhf(hn)));
                }
            } else {
                // out[t-1] = th_t w_o^T + b_o - x[t-1]
                const int o = g2_obase + row;
                const float boo = b_o[o];
                const int b0 = g2_bbase + quad * 4;
                const int tbase = (t - 1) * BATCH * ODIM;
                #pragma unroll
                for (int r = 0; r < 4; ++r) {
                    const int idx = tbase + (b0 + r) * ODIM + o;
                    out[idx] = acc[r] + boo - x[idx];   // flushed at kernel end
                }
            }
        }

        if (t < T_STEPS) {
            group_bar(flags, grp, wg, tid, target);
            target++;
        }
    }
}

extern "C" void kernel_launch(void* const* d_in, const int* in_sizes, int n_in,
                              void* d_out, int out_size, void* d_ws, size_t ws_size,
                              hipStream_t stream) {
    const float* x      = (const float*)d_in[0];
    const float* h_init = (const float*)d_in[1];
    const float* w_r    = (const float*)d_in[2];
    const float* b_r    = (const float*)d_in[3];
    const float* w_o    = (const float*)d_in[4];
    const float* b_o    = (const float*)d_in[5];
    float* out = (float*)d_out;
    char*  ws  = (char*)d_ws;

    // zero the barrier flags (ws is poisoned 0xAA before every launch)
    (void)hipMemsetAsync(ws + FLAG_OFF, 0, NWG * 64, stream);

    trnn_persistent<<<dim3(NWG), dim3(NTHR), 0, stream>>>(
        x, h_init, w_r, b_r, w_o, b_o, out, ws);
}